// Round 15
// baseline (322.743 us; speedup 1.0000x reference)
//
#include <hip/hip_runtime.h>

#define NROWS 32768
#define DIM   512
#define KC    1024

typedef __attribute__((ext_vector_type(8)))  short short8v;
typedef __attribute__((ext_vector_type(16))) float f32x16;
typedef __attribute__((ext_vector_type(4)))  float f32x4;

#define AS1 __attribute__((address_space(1)))
#define AS3 __attribute__((address_space(3)))

// RTN float -> bf16(short), plus residual bf16
__device__ __forceinline__ void split_bf16(float v, short& hi, short& lo) {
    unsigned u = __float_as_uint(v);
    unsigned r = u + 0x7FFFu + ((u >> 16) & 1u);
    hi = (short)(r >> 16);
    float hif = __uint_as_float(r & 0xFFFF0000u);
    float rem = v - hif;
    unsigned u2 = __float_as_uint(rem);
    unsigned r2 = u2 + 0x7FFFu + ((u2 >> 16) & 1u);
    lo = (short)(r2 >> 16);
}

__device__ __forceinline__ void conv8(const float4 a, const float4 b,
                                      short8v& hi, short8v& lo) {
    short h, l;
    split_bf16(a.x, h, l); hi[0] = h; lo[0] = l;
    split_bf16(a.y, h, l); hi[1] = h; lo[1] = l;
    split_bf16(a.z, h, l); hi[2] = h; lo[2] = l;
    split_bf16(a.w, h, l); hi[3] = h; lo[3] = l;
    split_bf16(b.x, h, l); hi[4] = h; lo[4] = l;
    split_bf16(b.y, h, l); hi[5] = h; lo[5] = l;
    split_bf16(b.z, h, l); hi[6] = h; lo[6] = l;
    split_bf16(b.w, h, l); hi[7] = h; lo[7] = l;
}

__device__ __forceinline__ unsigned long long pack_key(float d, int c) {
    unsigned u = __float_as_uint(d);
    u = (u & 0x80000000u) ? ~u : (u | 0x80000000u);   // monotone for min
    return ((unsigned long long)u << 32) | (unsigned)c;
}

// ---------------- E prep: frag-convert + en2 + inits (32 blocks) ----------
// efrag per 32-row group: [kb 0..31][h 0..1][lane 0..63][8 shorts]
__global__ __launch_bounds__(256) void k_eprep(const float* __restrict__ E,
                                               short* __restrict__ efrag,
                                               float* __restrict__ en2,
                                               int* __restrict__ counts,
                                               unsigned long long* __restrict__ packed) {
    __shared__ short hbuf[32][520];
    __shared__ short lbuf[32][520];
    int b = blockIdx.x, t = threadIdx.x;
    const float* src = E + (size_t)b * 32 * DIM;
    short* dst = efrag + (size_t)b * 32768;

    unsigned long long* p = packed + b * 1024;
    #pragma unroll
    for (int i = 0; i < 4; ++i) p[t + i * 256] = 0xFFFFFFFFFFFFFFFFull;
    if (b == 0) {
        #pragma unroll
        for (int i = 0; i < 4; ++i) counts[t + i * 256] = 0;
    }

    #pragma unroll
    for (int f = 0; f < 16; ++f) {
        int u = t + f * 256;
        int row = u >> 7, c4 = (u & 127) * 4;
        float4 v = *reinterpret_cast<const float4*>(&src[row * DIM + c4]);
        short4 h4, l4;
        split_bf16(v.x, h4.x, l4.x); split_bf16(v.y, h4.y, l4.y);
        split_bf16(v.z, h4.z, l4.z); split_bf16(v.w, h4.w, l4.w);
        *reinterpret_cast<short4*>(&hbuf[row][c4]) = h4;
        *reinterpret_cast<short4*>(&lbuf[row][c4]) = l4;
    }
    __syncthreads();
    #pragma unroll
    for (int f = 0; f < 16; ++f) {
        int u = t + f * 256;
        int lane = u & 63, h = (u >> 6) & 1, kb = u >> 7;
        int row = lane & 31, k0 = kb * 16 + (lane >> 5) * 8;
        const short* s = h ? &lbuf[row][k0] : &hbuf[row][k0];
        short8v val = *reinterpret_cast<const short8v*>(s);
        *reinterpret_cast<short8v*>(&dst[(size_t)u * 8]) = val;
    }

    // en2: wave w handles codes b*32 + w*8 .. +7
    int w = t >> 6, lane = t & 63;
    for (int cc = 0; cc < 8; ++cc) {
        int c = b * 32 + w * 8 + cc;
        const float* row = E + (size_t)c * DIM;
        float4 a = *reinterpret_cast<const float4*>(&row[lane * 8]);
        float4 bb = *reinterpret_cast<const float4*>(&row[lane * 8 + 4]);
        float s = a.x*a.x + a.y*a.y + a.z*a.z + a.w*a.w
                + bb.x*bb.x + bb.y*bb.y + bb.z*bb.z + bb.w*bb.w;
        #pragma unroll
        for (int off = 32; off; off >>= 1) s += __shfl_xor(s, off);
        if (!lane) en2[c] = s;
    }
}

// ---------------- argmin: x-direct, DMA-B, 3-deep pipelined MFMA GEMM -----
// (round-9 structure, best measured). block tile 128 rows x 256 codes,
// 4 waves each 64x128 (2m x 4n mfma 32x32). A (x): fp32 loads -> conv8 ->
// ds_write slots 0..7. B (efrag): 16 x 1KB chunks DMA'd into slots 8..23.
// 3-buffer pipeline, counted vmcnt(4). MFMA as 3 passes of 8 independent
// ops; per-accumulator order (hh->hl->lh) unchanged => bit-identical.
__global__ __launch_bounds__(256, 2) void k_argmin(const float* __restrict__ x,
                                                   const short* __restrict__ efrag,
                                                   const float* __restrict__ en2,
                                                   unsigned long long* __restrict__ packed) {
    __shared__ short sbuf[3][12288];      // 3 x 24 KB
    const int tid = threadIdx.x;
    const int w = tid >> 6, l = tid & 63;
    const int wr = w >> 1, wc = w & 1;
    const int l31 = l & 31, lh = l >> 5;

    int bid = blockIdx.x;                 // 1024 blocks
    int xcd = bid & 7, j = bid >> 3;      // j 0..127
    int row0 = (xcd * 32 + (j >> 2)) * 128;
    int c0   = (j & 3) * 256;

    const float* axsrc = x + (size_t)(row0 + w * 32 + l31) * DIM + lh * 8;
    const short* gsrc[4];
    #pragma unroll
    for (int s = 0; s < 4; ++s) {
        int gb = w * 2 + (s >> 1), h = s & 1;
        gsrc[s] = efrag + (size_t)(c0 / 32 + gb) * 32768 + h * 512 + l * 8;
    }

    f32x16 acc[2][4];
    #pragma unroll
    for (int a = 0; a < 2; ++a)
        #pragma unroll
        for (int b = 0; b < 4; ++b)
            #pragma unroll
            for (int r = 0; r < 16; ++r) acc[a][b][r] = 0.f;

    // prologue: A0, B0, A1, B1 (issue order matters for vmcnt counting)
    float4 a00 = *reinterpret_cast<const float4*>(axsrc);
    float4 a01 = *reinterpret_cast<const float4*>(axsrc + 4);
    __builtin_amdgcn_sched_barrier(0);
    #pragma unroll
    for (int s = 0; s < 4; ++s)
        __builtin_amdgcn_global_load_lds((const AS1 void*)gsrc[s],
                                         (AS3 void*)&sbuf[0][(8 + w * 4 + s) * 512],
                                         16, 0, 0);
    __builtin_amdgcn_sched_barrier(0);
    float4 a10 = *reinterpret_cast<const float4*>(axsrc + 16);
    float4 a11 = *reinterpret_cast<const float4*>(axsrc + 20);
    __builtin_amdgcn_sched_barrier(0);
    #pragma unroll
    for (int s = 0; s < 4; ++s)
        __builtin_amdgcn_global_load_lds((const AS1 void*)(gsrc[s] + 1024),
                                         (AS3 void*)&sbuf[1][(8 + w * 4 + s) * 512],
                                         16, 0, 0);
    {
        asm volatile("s_waitcnt vmcnt(10)" ::: "memory");   // A0 done
        short8v hi, lo; conv8(a00, a01, hi, lo);
        *reinterpret_cast<short8v*>(&sbuf[0][(w * 2 + 0) * 512 + l * 8]) = hi;
        *reinterpret_cast<short8v*>(&sbuf[0][(w * 2 + 1) * 512 + l * 8]) = lo;
        asm volatile("s_waitcnt vmcnt(4)" ::: "memory");    // A1 + B0 done
        conv8(a10, a11, hi, lo);
        *reinterpret_cast<short8v*>(&sbuf[1][(w * 2 + 0) * 512 + l * 8]) = hi;
        *reinterpret_cast<short8v*>(&sbuf[1][(w * 2 + 1) * 512 + l * 8]) = lo;
        asm volatile("s_waitcnt lgkmcnt(0)" ::: "memory");
        __builtin_amdgcn_s_barrier();
    }

    #pragma unroll 3
    for (int kb = 0; kb < 30; ++kb) {
        const int cur = kb % 3, nxt = (kb + 2) % 3;
        float4 an0 = *reinterpret_cast<const float4*>(axsrc + (kb + 2) * 16);
        float4 an1 = *reinterpret_cast<const float4*>(axsrc + (kb + 2) * 16 + 4);
        __builtin_amdgcn_sched_barrier(0);
        #pragma unroll
        for (int s = 0; s < 4; ++s)
            __builtin_amdgcn_global_load_lds(
                (const AS1 void*)(gsrc[s] + (size_t)(kb + 2) * 1024),
                (AS3 void*)&sbuf[nxt][(8 + w * 4 + s) * 512], 16, 0, 0);
        {
            short8v ah[2], al[2], bh[4], bl[4];
            const short* sb = sbuf[cur];
            #pragma unroll
            for (int m = 0; m < 2; ++m) {
                int g = wr * 2 + m;
                ah[m] = *reinterpret_cast<const short8v*>(&sb[(g * 2 + 0) * 512 + l * 8]);
                al[m] = *reinterpret_cast<const short8v*>(&sb[(g * 2 + 1) * 512 + l * 8]);
            }
            #pragma unroll
            for (int n = 0; n < 4; ++n) {
                int g = 4 + wc * 4 + n;
                bh[n] = *reinterpret_cast<const short8v*>(&sb[(g * 2 + 0) * 512 + l * 8]);
                bl[n] = *reinterpret_cast<const short8v*>(&sb[(g * 2 + 1) * 512 + l * 8]);
            }
            #pragma unroll
            for (int m = 0; m < 2; ++m)
                #pragma unroll
                for (int n = 0; n < 4; ++n)
                    acc[m][n] = __builtin_amdgcn_mfma_f32_32x32x16_bf16(
                        ah[m], bh[n], acc[m][n], 0, 0, 0);
            #pragma unroll
            for (int m = 0; m < 2; ++m)
                #pragma unroll
                for (int n = 0; n < 4; ++n)
                    acc[m][n] = __builtin_amdgcn_mfma_f32_32x32x16_bf16(
                        ah[m], bl[n], acc[m][n], 0, 0, 0);
            #pragma unroll
            for (int m = 0; m < 2; ++m)
                #pragma unroll
                for (int n = 0; n < 4; ++n)
                    acc[m][n] = __builtin_amdgcn_mfma_f32_32x32x16_bf16(
                        al[m], bh[n], acc[m][n], 0, 0, 0);
        }
        asm volatile("s_waitcnt vmcnt(4)" ::: "memory");
        {
            short8v hi, lo; conv8(an0, an1, hi, lo);
            *reinterpret_cast<short8v*>(&sbuf[nxt][(w * 2 + 0) * 512 + l * 8]) = hi;
            *reinterpret_cast<short8v*>(&sbuf[nxt][(w * 2 + 1) * 512 + l * 8]) = lo;
        }
        asm volatile("s_waitcnt lgkmcnt(0)" ::: "memory");
        __builtin_amdgcn_s_barrier();
    }

    #pragma unroll
    for (int e = 0; e < 2; ++e) {
        const int kb = 30 + e, cur = kb % 3;
        short8v ah[2], al[2], bh[4], bl[4];
        const short* sb = sbuf[cur];
        #pragma unroll
        for (int m = 0; m < 2; ++m) {
            int g = wr * 2 + m;
            ah[m] = *reinterpret_cast<const short8v*>(&sb[(g * 2 + 0) * 512 + l * 8]);
            al[m] = *reinterpret_cast<const short8v*>(&sb[(g * 2 + 1) * 512 + l * 8]);
        }
        #pragma unroll
        for (int n = 0; n < 4; ++n) {
            int g = 4 + wc * 4 + n;
            bh[n] = *reinterpret_cast<const short8v*>(&sb[(g * 2 + 0) * 512 + l * 8]);
            bl[n] = *reinterpret_cast<const short8v*>(&sb[(g * 2 + 1) * 512 + l * 8]);
        }
        #pragma unroll
        for (int m = 0; m < 2; ++m)
            #pragma unroll
            for (int n = 0; n < 4; ++n)
                acc[m][n] = __builtin_amdgcn_mfma_f32_32x32x16_bf16(
                    ah[m], bh[n], acc[m][n], 0, 0, 0);
        #pragma unroll
        for (int m = 0; m < 2; ++m)
            #pragma unroll
            for (int n = 0; n < 4; ++n)
                acc[m][n] = __builtin_amdgcn_mfma_f32_32x32x16_bf16(
                    ah[m], bl[n], acc[m][n], 0, 0, 0);
        #pragma unroll
        for (int m = 0; m < 2; ++m)
            #pragma unroll
            for (int n = 0; n < 4; ++n)
                acc[m][n] = __builtin_amdgcn_mfma_f32_32x32x16_bf16(
                    al[m], bh[n], acc[m][n], 0, 0, 0);
        if (e == 0) {
            asm volatile("s_waitcnt vmcnt(0) lgkmcnt(0)" ::: "memory");
            __builtin_amdgcn_s_barrier();
        }
    }

    // epilogue: dist = ||e||^2 - 2 x.e ; D layout: col=l&31,
    // row=(r&3)+8*(r>>2)+4*(l>>5)
    float e2[4];
    #pragma unroll
    for (int n = 0; n < 4; ++n) e2[n] = en2[c0 + wc * 128 + n * 32 + l31];
    #pragma unroll
    for (int m = 0; m < 2; ++m) {
        #pragma unroll
        for (int r = 0; r < 16; ++r) {
            unsigned long long key = 0xFFFFFFFFFFFFFFFFull;
            #pragma unroll
            for (int n = 0; n < 4; ++n) {
                float d = fmaf(-2.f, acc[m][n][r], e2[n]);
                unsigned long long k = pack_key(d, c0 + wc * 128 + n * 32 + l31);
                if (k < key) key = k;
            }
            #pragma unroll
            for (int off = 1; off < 32; off <<= 1) {
                unsigned long long o = __shfl_xor(key, off);
                if (o < key) key = o;
            }
            if (l31 == 0) {
                int grow = row0 + wr * 64 + m * 32 + (r & 3) + 8 * (r >> 2) + 4 * lh;
                atomicMin(&packed[grow], key);
            }
        }
    }
}

// ---------------- unpack idx + histogram ----------------
__global__ __launch_bounds__(256) void k_hist(const unsigned long long* __restrict__ packed,
                                              int* __restrict__ idx,
                                              int* __restrict__ counts) {
    __shared__ int h[KC];
    for (int i = threadIdx.x; i < KC; i += 256) h[i] = 0;
    __syncthreads();
    int g = blockIdx.x * 256 + threadIdx.x;
    int c = (int)(unsigned)(packed[g] & 0xFFFFFFFFull);
    idx[g] = c;
    atomicAdd(&h[c], 1);
    __syncthreads();
    for (int i = threadIdx.x; i < KC; i += 256)
        if (h[i]) atomicAdd(&counts[i], h[i]);
}

// ---------------- smoothing, perplexity, prefix sums (1-barrier) ----------
__global__ __launch_bounds__(1024) void k_meta(const int* __restrict__ counts,
                                               const float* __restrict__ ema_cs,
                                               float* __restrict__ smoothed,
                                               int* __restrict__ offsets,
                                               int* __restrict__ cursor,
                                               float* __restrict__ perp_out) {
    __shared__ float ws1[16], ws2[16];
    __shared__ int wsum[16];
    int t = threadIdx.x, lane = t & 63, w = t >> 6;
    int cnt = counts[t];
    float cs = ema_cs[t] * 0.99f + 0.01f * (float)cnt;
    float p = (float)cnt / 32768.f;
    float v1 = cs, v2 = p * logf(p + 1e-10f);
    #pragma unroll
    for (int off = 32; off; off >>= 1) {
        v1 += __shfl_xor(v1, off);
        v2 += __shfl_xor(v2, off);
    }
    int s = cnt;
    #pragma unroll
    for (int off = 1; off < 64; off <<= 1) {
        int u = __shfl_up(s, off);
        if (lane >= off) s += u;
    }
    if (lane == 0) { ws1[w] = v1; ws2[w] = v2; }
    if (lane == 63) wsum[w] = s;
    __syncthreads();
    float n = 0.f;
    #pragma unroll
    for (int i = 0; i < 16; ++i) n += ws1[i];
    smoothed[t] = (cs + 1e-5f) / (n + 1024.f * 1e-5f) * n;
    if (t == 0) {
        float sp = 0.f;
        #pragma unroll
        for (int i = 0; i < 16; ++i) sp += ws2[i];
        perp_out[0] = expf(-sp);
    }
    int wo = 0;
    for (int i = 0; i < 16; ++i) if (i < w) wo += wsum[i];
    int off_ = wo + s - cnt;   // exclusive prefix (exact int)
    offsets[t] = off_;
    cursor[t] = off_;
}

// ---------------- CSR bucket scatter ----------------
__global__ __launch_bounds__(256) void k_scatter(const int* __restrict__ idx,
                                                 int* __restrict__ cursor,
                                                 int* __restrict__ bucket) {
    int g = blockIdx.x * 256 + threadIdx.x;
    int c = idx[g];
    int pos = atomicAdd(&cursor[c], 1);
    bucket[pos] = g;
}

// ---------------- segment-sum + new embedding + enc one-hot writer -------
// block (k, half): gathers x rows of bucket[k] for dims [half*256,+256),
// writes newE, AND writes enc[r][half*512 .. +512) for each bucket row
// (value (col==k); every row is in exactly one bucket -> full coverage).
// enc writes are fire-and-forget, hidden under the gather latency.
__global__ __launch_bounds__(256) void k_dw(const float* __restrict__ x,
                                            const float* __restrict__ ema_w,
                                            const int* __restrict__ offsets,
                                            const int* __restrict__ counts,
                                            const int* __restrict__ bucket,
                                            const float* __restrict__ smoothed,
                                            float* __restrict__ newE,
                                            float* __restrict__ enc) {
    __shared__ int rows[256];
    int k = blockIdx.x >> 1, half = blockIdx.x & 1, t = threadIdx.x;
    int d = half * 256 + t;
    int beg = offsets[k], m = counts[k];
    // one-hot payload for this thread's enc slots (2 slots of 4 cols each)
    int ecol0 = half * 512 + (t & 127) * 4;
    f32x4 ev;
    ev[0] = (ecol0 == k)     ? 1.f : 0.f;
    ev[1] = (ecol0 + 1 == k) ? 1.f : 0.f;
    ev[2] = (ecol0 + 2 == k) ? 1.f : 0.f;
    ev[3] = (ecol0 + 3 == k) ? 1.f : 0.f;

    float a = 0.f;
    for (int base = 0; base < m; base += 256) {
        int n = min(256, m - base);
        __syncthreads();
        if (t < n) rows[t] = bucket[beg + base + t];
        __syncthreads();
        // enc writes for this chunk: 2 rows per pass, 128 threads per row
        for (int i = 0; i < n; i += 2) {
            int ri = i + (t >> 7);
            if (ri < n) {
                float* dst = enc + (size_t)rows[ri] * KC + half * 512;
                *reinterpret_cast<f32x4*>(&dst[(t & 127) * 4]) = ev;
            }
        }
        int i = 0;
        for (; i + 4 <= n; i += 4) {
            float v0 = x[(size_t)rows[i]     * DIM + d];
            float v1 = x[(size_t)rows[i + 1] * DIM + d];
            float v2 = x[(size_t)rows[i + 2] * DIM + d];
            float v3 = x[(size_t)rows[i + 3] * DIM + d];
            a += v0 + v1 + v2 + v3;
        }
        for (; i < n; ++i) a += x[(size_t)rows[i] * DIM + d];
    }
    newE[(size_t)k * DIM + d] =
        (ema_w[(size_t)k * DIM + d] * 0.99f + 0.01f * a) / smoothed[k];
}

// ---------------- fused quantized (STE) + loss partials ----------------
__global__ __launch_bounds__(256) void k_qe(const float* __restrict__ x,
                                            const int* __restrict__ idx,
                                            const float* __restrict__ newE,
                                            float* __restrict__ outq,
                                            float* __restrict__ partials) {
    int b = blockIdx.x, t = threadIdx.x;
    int row8 = b * 8;
    float lp = 0.f;
    #pragma unroll
    for (int it = 0; it < 4; ++it) {
        int slot = t + it * 256;
        int r = slot >> 7;
        int c4 = (slot & 127) * 4;
        int row = row8 + r;
        int code = idx[row];
        float4 in = *reinterpret_cast<const float4*>(&x[(size_t)row * DIM + c4]);
        float4 q  = *reinterpret_cast<const float4*>(&newE[(size_t)code * DIM + c4]);
        float4 d;
        d.x = q.x - in.x; d.y = q.y - in.y; d.z = q.z - in.z; d.w = q.w - in.w;
        float4 o;
        o.x = in.x + d.x; o.y = in.y + d.y; o.z = in.z + d.z; o.w = in.w + d.w;
        *reinterpret_cast<float4*>(&outq[(size_t)row * DIM + c4]) = o;
        lp += d.x*d.x + d.y*d.y + d.z*d.z + d.w*d.w;
    }
    #pragma unroll
    for (int off = 32; off; off >>= 1) lp += __shfl_xor(lp, off);
    __shared__ float wr[4];
    int lane = t & 63, w = t >> 6;
    if (!lane) wr[w] = lp;
    __syncthreads();
    if (t == 0) partials[b] = wr[0] + wr[1] + wr[2] + wr[3];
}

__global__ __launch_bounds__(256) void k_lossfin(const float* __restrict__ partials,
                                                 float* __restrict__ out0) {
    __shared__ double red[256];
    double s = 0.0;
    for (int i = threadIdx.x; i < 4096; i += 256) s += (double)partials[i];
    red[threadIdx.x] = s; __syncthreads();
    for (int st = 128; st; st >>= 1) {
        if (threadIdx.x < st) red[threadIdx.x] += red[threadIdx.x + st];
        __syncthreads();
    }
    if (!threadIdx.x) out0[0] = (float)(0.25 * red[0] / 16777216.0);
}

extern "C" void kernel_launch(void* const* d_in, const int* in_sizes, int n_in,
                              void* d_out, int out_size, void* d_ws, size_t ws_size,
                              hipStream_t stream) {
    const float* x   = (const float*)d_in[0];
    const float* E   = (const float*)d_in[1];
    const float* ecs = (const float*)d_in[2];
    const float* emw = (const float*)d_in[3];
    float* out = (float*)d_out;

    char* ws = (char*)d_ws;
    int*   idx      = (int*)(ws + 0);                  // 128 KB
    int*   bucket   = (int*)(ws + 131072);             // 128 KB
    float* en2      = (float*)(ws + 262144);           // 4 KB
    int*   counts   = (int*)(ws + 266240);             // 4 KB
    int*   offsets  = (int*)(ws + 270336);             // 4 KB
    int*   cursor   = (int*)(ws + 274432);             // 4 KB
    float* smoothed = (float*)(ws + 278528);           // 4 KB
    float* newE     = (float*)(ws + 282624);           // 2 MB
    float* partials = (float*)(ws + 282624 + 2097152); // 16 KB
    unsigned long long* packed = (unsigned long long*)newE;  // dead before k_dw

    float* out_loss = out;
    float* out_q    = out + 1;
    float* out_perp = out + 16777217;
    float* out_enc  = out + 16777218;

    // efrag scratch lives in out_enc (2 MB of 128 MB; enc is rewritten in
    // full by k_dw afterwards -- every row is in exactly one bucket)
    short* efrag = (short*)out_enc;

    k_eprep  <<<KC / 32, 256, 0, stream>>>(E, efrag, en2, counts, packed);
    k_argmin <<<(NROWS / 128) * 4, 256, 0, stream>>>(x, efrag, en2, packed);
    k_hist   <<<NROWS / 256, 256, 0, stream>>>(packed, idx, counts);
    k_meta   <<<1, 1024, 0, stream>>>(counts, ecs, smoothed, offsets, cursor, out_perp);
    k_scatter<<<NROWS / 256, 256, 0, stream>>>(idx, cursor, bucket);
    k_dw     <<<KC * 2, 256, 0, stream>>>(x, emw, offsets, counts, bucket, smoothed,
                                          newE, out_enc);
    k_qe     <<<NROWS / 8, 256, 0, stream>>>(x, idx, newE, out_q, partials);
    k_lossfin<<<1, 256, 0, stream>>>(partials, out_loss);
}

// Round 16
// 279.017 us; speedup vs baseline: 1.1567x; 1.1567x over previous
//
#include <hip/hip_runtime.h>

#define NROWS 32768
#define DIM   512
#define KC    1024

typedef __attribute__((ext_vector_type(8)))  short short8v;
typedef __attribute__((ext_vector_type(16))) float f32x16;

#define AS1 __attribute__((address_space(1)))
#define AS3 __attribute__((address_space(3)))

// RTN float -> bf16(short), plus residual bf16
__device__ __forceinline__ void split_bf16(float v, short& hi, short& lo) {
    unsigned u = __float_as_uint(v);
    unsigned r = u + 0x7FFFu + ((u >> 16) & 1u);
    hi = (short)(r >> 16);
    float hif = __uint_as_float(r & 0xFFFF0000u);
    float rem = v - hif;
    unsigned u2 = __float_as_uint(rem);
    unsigned r2 = u2 + 0x7FFFu + ((u2 >> 16) & 1u);
    lo = (short)(r2 >> 16);
}

__device__ __forceinline__ void conv8(const float4 a, const float4 b,
                                      short8v& hi, short8v& lo) {
    short h, l;
    split_bf16(a.x, h, l); hi[0] = h; lo[0] = l;
    split_bf16(a.y, h, l); hi[1] = h; lo[1] = l;
    split_bf16(a.z, h, l); hi[2] = h; lo[2] = l;
    split_bf16(a.w, h, l); hi[3] = h; lo[3] = l;
    split_bf16(b.x, h, l); hi[4] = h; lo[4] = l;
    split_bf16(b.y, h, l); hi[5] = h; lo[5] = l;
    split_bf16(b.z, h, l); hi[6] = h; lo[6] = l;
    split_bf16(b.w, h, l); hi[7] = h; lo[7] = l;
}

__device__ __forceinline__ unsigned long long pack_key(float d, int c) {
    unsigned u = __float_as_uint(d);
    u = (u & 0x80000000u) ? ~u : (u | 0x80000000u);   // monotone for min
    return ((unsigned long long)u << 32) | (unsigned)c;
}

// ---------------- E prep: frag-convert + en2 + inits (32 blocks) ----------
// efrag per 32-row group: [kb 0..31][h 0..1][lane 0..63][8 shorts]
// also zeroes the 2 MB dw-accumulator and counts, inits packed keys.
__global__ __launch_bounds__(256) void k_eprep(const float* __restrict__ E,
                                               short* __restrict__ efrag,
                                               float* __restrict__ en2,
                                               int* __restrict__ counts,
                                               unsigned long long* __restrict__ packed,
                                               float* __restrict__ accb) {
    __shared__ short hbuf[32][520];
    __shared__ short lbuf[32][520];
    int b = blockIdx.x, t = threadIdx.x;
    const float* src = E + (size_t)b * 32 * DIM;
    short* dst = efrag + (size_t)b * 32768;

    unsigned long long* p = packed + b * 1024;
    #pragma unroll
    for (int i = 0; i < 4; ++i) p[t + i * 256] = 0xFFFFFFFFFFFFFFFFull;
    if (b == 0) {
        #pragma unroll
        for (int i = 0; i < 4; ++i) counts[t + i * 256] = 0;
    }
    // zero this block's 16384-float slice of accb
    {
        float* az = accb + (size_t)b * 16384;
        #pragma unroll
        for (int i = 0; i < 64; ++i) az[t + i * 256] = 0.f;
    }

    #pragma unroll
    for (int f = 0; f < 16; ++f) {
        int u = t + f * 256;
        int row = u >> 7, c4 = (u & 127) * 4;
        float4 v = *reinterpret_cast<const float4*>(&src[row * DIM + c4]);
        short4 h4, l4;
        split_bf16(v.x, h4.x, l4.x); split_bf16(v.y, h4.y, l4.y);
        split_bf16(v.z, h4.z, l4.z); split_bf16(v.w, h4.w, l4.w);
        *reinterpret_cast<short4*>(&hbuf[row][c4]) = h4;
        *reinterpret_cast<short4*>(&lbuf[row][c4]) = l4;
    }
    __syncthreads();
    #pragma unroll
    for (int f = 0; f < 16; ++f) {
        int u = t + f * 256;
        int lane = u & 63, h = (u >> 6) & 1, kb = u >> 7;
        int row = lane & 31, k0 = kb * 16 + (lane >> 5) * 8;
        const short* s = h ? &lbuf[row][k0] : &hbuf[row][k0];
        short8v val = *reinterpret_cast<const short8v*>(s);
        *reinterpret_cast<short8v*>(&dst[(size_t)u * 8]) = val;
    }

    // en2: wave w handles codes b*32 + w*8 .. +7
    int w = t >> 6, lane = t & 63;
    for (int cc = 0; cc < 8; ++cc) {
        int c = b * 32 + w * 8 + cc;
        const float* row = E + (size_t)c * DIM;
        float4 a = *reinterpret_cast<const float4*>(&row[lane * 8]);
        float4 bb = *reinterpret_cast<const float4*>(&row[lane * 8 + 4]);
        float s = a.x*a.x + a.y*a.y + a.z*a.z + a.w*a.w
                + bb.x*bb.x + bb.y*bb.y + bb.z*bb.z + bb.w*bb.w;
        #pragma unroll
        for (int off = 32; off; off >>= 1) s += __shfl_xor(s, off);
        if (!lane) en2[c] = s;
    }
}

// ---------------- argmin: x-direct, DMA-B, 3-deep pipelined MFMA GEMM -----
// (round-9 structure, best measured.) block tile 128 rows x 256 codes,
// 4 waves each 64x128 (2m x 4n mfma 32x32). 3-buffer pipeline, counted
// vmcnt(4). MFMA as 3 passes of 8 independent ops; per-accumulator order
// (hh->hl->lh) unchanged => bit-identical.
__global__ __launch_bounds__(256, 2) void k_argmin(const float* __restrict__ x,
                                                   const short* __restrict__ efrag,
                                                   const float* __restrict__ en2,
                                                   unsigned long long* __restrict__ packed) {
    __shared__ short sbuf[3][12288];      // 3 x 24 KB
    const int tid = threadIdx.x;
    const int w = tid >> 6, l = tid & 63;
    const int wr = w >> 1, wc = w & 1;
    const int l31 = l & 31, lh = l >> 5;

    int bid = blockIdx.x;                 // 1024 blocks
    int xcd = bid & 7, j = bid >> 3;      // j 0..127
    int row0 = (xcd * 32 + (j >> 2)) * 128;
    int c0   = (j & 3) * 256;

    const float* axsrc = x + (size_t)(row0 + w * 32 + l31) * DIM + lh * 8;
    const short* gsrc[4];
    #pragma unroll
    for (int s = 0; s < 4; ++s) {
        int gb = w * 2 + (s >> 1), h = s & 1;
        gsrc[s] = efrag + (size_t)(c0 / 32 + gb) * 32768 + h * 512 + l * 8;
    }

    f32x16 acc[2][4];
    #pragma unroll
    for (int a = 0; a < 2; ++a)
        #pragma unroll
        for (int b = 0; b < 4; ++b)
            #pragma unroll
            for (int r = 0; r < 16; ++r) acc[a][b][r] = 0.f;

    // prologue: A0, B0, A1, B1 (issue order matters for vmcnt counting)
    float4 a00 = *reinterpret_cast<const float4*>(axsrc);
    float4 a01 = *reinterpret_cast<const float4*>(axsrc + 4);
    __builtin_amdgcn_sched_barrier(0);
    #pragma unroll
    for (int s = 0; s < 4; ++s)
        __builtin_amdgcn_global_load_lds((const AS1 void*)gsrc[s],
                                         (AS3 void*)&sbuf[0][(8 + w * 4 + s) * 512],
                                         16, 0, 0);
    __builtin_amdgcn_sched_barrier(0);
    float4 a10 = *reinterpret_cast<const float4*>(axsrc + 16);
    float4 a11 = *reinterpret_cast<const float4*>(axsrc + 20);
    __builtin_amdgcn_sched_barrier(0);
    #pragma unroll
    for (int s = 0; s < 4; ++s)
        __builtin_amdgcn_global_load_lds((const AS1 void*)(gsrc[s] + 1024),
                                         (AS3 void*)&sbuf[1][(8 + w * 4 + s) * 512],
                                         16, 0, 0);
    {
        asm volatile("s_waitcnt vmcnt(10)" ::: "memory");   // A0 done
        short8v hi, lo; conv8(a00, a01, hi, lo);
        *reinterpret_cast<short8v*>(&sbuf[0][(w * 2 + 0) * 512 + l * 8]) = hi;
        *reinterpret_cast<short8v*>(&sbuf[0][(w * 2 + 1) * 512 + l * 8]) = lo;
        asm volatile("s_waitcnt vmcnt(4)" ::: "memory");    // A1 + B0 done
        conv8(a10, a11, hi, lo);
        *reinterpret_cast<short8v*>(&sbuf[1][(w * 2 + 0) * 512 + l * 8]) = hi;
        *reinterpret_cast<short8v*>(&sbuf[1][(w * 2 + 1) * 512 + l * 8]) = lo;
        asm volatile("s_waitcnt lgkmcnt(0)" ::: "memory");
        __builtin_amdgcn_s_barrier();
    }

    #pragma unroll 3
    for (int kb = 0; kb < 30; ++kb) {
        const int cur = kb % 3, nxt = (kb + 2) % 3;
        float4 an0 = *reinterpret_cast<const float4*>(axsrc + (kb + 2) * 16);
        float4 an1 = *reinterpret_cast<const float4*>(axsrc + (kb + 2) * 16 + 4);
        __builtin_amdgcn_sched_barrier(0);
        #pragma unroll
        for (int s = 0; s < 4; ++s)
            __builtin_amdgcn_global_load_lds(
                (const AS1 void*)(gsrc[s] + (size_t)(kb + 2) * 1024),
                (AS3 void*)&sbuf[nxt][(8 + w * 4 + s) * 512], 16, 0, 0);
        {
            short8v ah[2], al[2], bh[4], bl[4];
            const short* sb = sbuf[cur];
            #pragma unroll
            for (int m = 0; m < 2; ++m) {
                int g = wr * 2 + m;
                ah[m] = *reinterpret_cast<const short8v*>(&sb[(g * 2 + 0) * 512 + l * 8]);
                al[m] = *reinterpret_cast<const short8v*>(&sb[(g * 2 + 1) * 512 + l * 8]);
            }
            #pragma unroll
            for (int n = 0; n < 4; ++n) {
                int g = 4 + wc * 4 + n;
                bh[n] = *reinterpret_cast<const short8v*>(&sb[(g * 2 + 0) * 512 + l * 8]);
                bl[n] = *reinterpret_cast<const short8v*>(&sb[(g * 2 + 1) * 512 + l * 8]);
            }
            #pragma unroll
            for (int m = 0; m < 2; ++m)
                #pragma unroll
                for (int n = 0; n < 4; ++n)
                    acc[m][n] = __builtin_amdgcn_mfma_f32_32x32x16_bf16(
                        ah[m], bh[n], acc[m][n], 0, 0, 0);
            #pragma unroll
            for (int m = 0; m < 2; ++m)
                #pragma unroll
                for (int n = 0; n < 4; ++n)
                    acc[m][n] = __builtin_amdgcn_mfma_f32_32x32x16_bf16(
                        ah[m], bl[n], acc[m][n], 0, 0, 0);
            #pragma unroll
            for (int m = 0; m < 2; ++m)
                #pragma unroll
                for (int n = 0; n < 4; ++n)
                    acc[m][n] = __builtin_amdgcn_mfma_f32_32x32x16_bf16(
                        al[m], bh[n], acc[m][n], 0, 0, 0);
        }
        asm volatile("s_waitcnt vmcnt(4)" ::: "memory");
        {
            short8v hi, lo; conv8(an0, an1, hi, lo);
            *reinterpret_cast<short8v*>(&sbuf[nxt][(w * 2 + 0) * 512 + l * 8]) = hi;
            *reinterpret_cast<short8v*>(&sbuf[nxt][(w * 2 + 1) * 512 + l * 8]) = lo;
        }
        asm volatile("s_waitcnt lgkmcnt(0)" ::: "memory");
        __builtin_amdgcn_s_barrier();
    }

    #pragma unroll
    for (int e = 0; e < 2; ++e) {
        const int kb = 30 + e, cur = kb % 3;
        short8v ah[2], al[2], bh[4], bl[4];
        const short* sb = sbuf[cur];
        #pragma unroll
        for (int m = 0; m < 2; ++m) {
            int g = wr * 2 + m;
            ah[m] = *reinterpret_cast<const short8v*>(&sb[(g * 2 + 0) * 512 + l * 8]);
            al[m] = *reinterpret_cast<const short8v*>(&sb[(g * 2 + 1) * 512 + l * 8]);
        }
        #pragma unroll
        for (int n = 0; n < 4; ++n) {
            int g = 4 + wc * 4 + n;
            bh[n] = *reinterpret_cast<const short8v*>(&sb[(g * 2 + 0) * 512 + l * 8]);
            bl[n] = *reinterpret_cast<const short8v*>(&sb[(g * 2 + 1) * 512 + l * 8]);
        }
        #pragma unroll
        for (int m = 0; m < 2; ++m)
            #pragma unroll
            for (int n = 0; n < 4; ++n)
                acc[m][n] = __builtin_amdgcn_mfma_f32_32x32x16_bf16(
                    ah[m], bh[n], acc[m][n], 0, 0, 0);
        #pragma unroll
        for (int m = 0; m < 2; ++m)
            #pragma unroll
            for (int n = 0; n < 4; ++n)
                acc[m][n] = __builtin_amdgcn_mfma_f32_32x32x16_bf16(
                    ah[m], bl[n], acc[m][n], 0, 0, 0);
        #pragma unroll
        for (int m = 0; m < 2; ++m)
            #pragma unroll
            for (int n = 0; n < 4; ++n)
                acc[m][n] = __builtin_amdgcn_mfma_f32_32x32x16_bf16(
                    al[m], bh[n], acc[m][n], 0, 0, 0);
        if (e == 0) {
            asm volatile("s_waitcnt vmcnt(0) lgkmcnt(0)" ::: "memory");
            __builtin_amdgcn_s_barrier();
        }
    }

    // epilogue: dist = ||e||^2 - 2 x.e ; D layout: col=l&31,
    // row=(r&3)+8*(r>>2)+4*(l>>5)
    float e2[4];
    #pragma unroll
    for (int n = 0; n < 4; ++n) e2[n] = en2[c0 + wc * 128 + n * 32 + l31];
    #pragma unroll
    for (int m = 0; m < 2; ++m) {
        #pragma unroll
        for (int r = 0; r < 16; ++r) {
            unsigned long long key = 0xFFFFFFFFFFFFFFFFull;
            #pragma unroll
            for (int n = 0; n < 4; ++n) {
                float d = fmaf(-2.f, acc[m][n][r], e2[n]);
                unsigned long long k = pack_key(d, c0 + wc * 128 + n * 32 + l31);
                if (k < key) key = k;
            }
            #pragma unroll
            for (int off = 1; off < 32; off <<= 1) {
                unsigned long long o = __shfl_xor(key, off);
                if (o < key) key = o;
            }
            if (l31 == 0) {
                int grow = row0 + wr * 64 + m * 32 + (r & 3) + 8 * (r >> 2) + 4 * lh;
                atomicMin(&packed[grow], key);
            }
        }
    }
}

// ---------------- unpack idx + histogram ----------------
__global__ __launch_bounds__(256) void k_hist(const unsigned long long* __restrict__ packed,
                                              int* __restrict__ idx,
                                              int* __restrict__ counts) {
    __shared__ int h[KC];
    for (int i = threadIdx.x; i < KC; i += 256) h[i] = 0;
    __syncthreads();
    int g = blockIdx.x * 256 + threadIdx.x;
    int c = (int)(unsigned)(packed[g] & 0xFFFFFFFFull);
    idx[g] = c;
    atomicAdd(&h[c], 1);
    __syncthreads();
    for (int i = threadIdx.x; i < KC; i += 256)
        if (h[i]) atomicAdd(&counts[i], h[i]);
}

// ---------------- smoothing, perplexity, prefix sums (1-barrier) ----------
__global__ __launch_bounds__(1024) void k_meta(const int* __restrict__ counts,
                                               const float* __restrict__ ema_cs,
                                               float* __restrict__ smoothed,
                                               int* __restrict__ offsets,
                                               int* __restrict__ cursor,
                                               float* __restrict__ perp_out) {
    __shared__ float ws1[16], ws2[16];
    __shared__ int wsum[16];
    int t = threadIdx.x, lane = t & 63, w = t >> 6;
    int cnt = counts[t];
    float cs = ema_cs[t] * 0.99f + 0.01f * (float)cnt;
    float p = (float)cnt / 32768.f;
    float v1 = cs, v2 = p * logf(p + 1e-10f);
    #pragma unroll
    for (int off = 32; off; off >>= 1) {
        v1 += __shfl_xor(v1, off);
        v2 += __shfl_xor(v2, off);
    }
    int s = cnt;
    #pragma unroll
    for (int off = 1; off < 64; off <<= 1) {
        int u = __shfl_up(s, off);
        if (lane >= off) s += u;
    }
    if (lane == 0) { ws1[w] = v1; ws2[w] = v2; }
    if (lane == 63) wsum[w] = s;
    __syncthreads();
    float n = 0.f;
    #pragma unroll
    for (int i = 0; i < 16; ++i) n += ws1[i];
    smoothed[t] = (cs + 1e-5f) / (n + 1024.f * 1e-5f) * n;
    if (t == 0) {
        float sp = 0.f;
        #pragma unroll
        for (int i = 0; i < 16; ++i) sp += ws2[i];
        perp_out[0] = expf(-sp);
    }
    int wo = 0;
    for (int i = 0; i < 16; ++i) if (i < w) wo += wsum[i];
    int off_ = wo + s - cnt;   // exclusive prefix (exact int)
    offsets[t] = off_;
    cursor[t] = off_;
}

// ---------------- CSR bucket scatter ----------------
__global__ __launch_bounds__(256) void k_scatter(const int* __restrict__ idx,
                                                 int* __restrict__ cursor,
                                                 int* __restrict__ bucket) {
    int g = blockIdx.x * 256 + threadIdx.x;
    int c = idx[g];
    int pos = atomicAdd(&cursor[c], 1);
    bucket[pos] = g;
}

// ---------------- balanced segment-sum: 16 sub-blocks per (code,half) -----
// sub s of code k processes bucket chunks s, s+16, ... (256 rows each);
// partial sums fp32-atomicAdd'd into zeroed accb[k][d]. Splits the skewed
// hot-bucket tail 16 ways (occupancy was 9% from one-block-per-code).
__global__ __launch_bounds__(256) void k_dwacc(const float* __restrict__ x,
                                               const int* __restrict__ offsets,
                                               const int* __restrict__ counts,
                                               const int* __restrict__ bucket,
                                               float* __restrict__ accb) {
    __shared__ int rows[256];
    int bid = blockIdx.x;                 // 32768 blocks
    int k = bid >> 5, half = (bid >> 4) & 1, sub = bid & 15;
    int t = threadIdx.x;
    int d = half * 256 + t;
    int beg = offsets[k], m = counts[k];
    if (sub * 256 >= m) return;           // uniform per block
    float a = 0.f;
    for (int base = sub * 256; base < m; base += 4096) {
        int n = min(256, m - base);
        __syncthreads();
        if (t < n) rows[t] = bucket[beg + base + t];
        __syncthreads();
        int i = 0;
        for (; i + 4 <= n; i += 4) {
            float v0 = x[(size_t)rows[i]     * DIM + d];
            float v1 = x[(size_t)rows[i + 1] * DIM + d];
            float v2 = x[(size_t)rows[i + 2] * DIM + d];
            float v3 = x[(size_t)rows[i + 3] * DIM + d];
            a += v0 + v1 + v2 + v3;
        }
        for (; i < n; ++i) a += x[(size_t)rows[i] * DIM + d];
    }
    atomicAdd(&accb[(size_t)k * DIM + d], a);
}

// ---------------- finalize new embedding ----------------
__global__ __launch_bounds__(256) void k_fin(const float* __restrict__ accb,
                                             const float* __restrict__ ema_w,
                                             const float* __restrict__ smoothed,
                                             float* __restrict__ newE) {
    int g = blockIdx.x * 256 + threadIdx.x;   // 524288 elements
    int k = g >> 9;
    newE[g] = (ema_w[g] * 0.99f + 0.01f * accb[g]) / smoothed[k];
}

// ---------------- fused quantized (STE) + one-hot + loss partials ---------
// (round-9 version, measured-best)
__global__ __launch_bounds__(256) void k_qe(const float* __restrict__ x,
                                            const int* __restrict__ idx,
                                            const float* __restrict__ newE,
                                            float* __restrict__ outq,
                                            float* __restrict__ enc,
                                            float* __restrict__ partials) {
    int b = blockIdx.x, t = threadIdx.x;
    int row8 = b * 8;
    float lp = 0.f;
    #pragma unroll
    for (int it = 0; it < 4; ++it) {
        int slot = t + it * 256;
        int r = slot >> 7;
        int c4 = (slot & 127) * 4;
        int row = row8 + r;
        int code = idx[row];
        float4 in = *reinterpret_cast<const float4*>(&x[(size_t)row * DIM + c4]);
        float4 q  = *reinterpret_cast<const float4*>(&newE[(size_t)code * DIM + c4]);
        float4 d;
        d.x = q.x - in.x; d.y = q.y - in.y; d.z = q.z - in.z; d.w = q.w - in.w;
        float4 o;
        o.x = in.x + d.x; o.y = in.y + d.y; o.z = in.z + d.z; o.w = in.w + d.w;
        *reinterpret_cast<float4*>(&outq[(size_t)row * DIM + c4]) = o;
        lp += d.x*d.x + d.y*d.y + d.z*d.z + d.w*d.w;
    }
    {
        int er = row8 + (t >> 5);
        int l32 = t & 31;
        int one = idx[er];
        float4* dst = reinterpret_cast<float4*>(enc + (size_t)er * KC);
        #pragma unroll
        for (int s = 0; s < 8; ++s) {
            int c4 = l32 + s * 32;
            int base = c4 * 4;
            float4 v;
            v.x = (one == base)     ? 1.f : 0.f;
            v.y = (one == base + 1) ? 1.f : 0.f;
            v.z = (one == base + 2) ? 1.f : 0.f;
            v.w = (one == base + 3) ? 1.f : 0.f;
            dst[c4] = v;
        }
    }
    #pragma unroll
    for (int off = 32; off; off >>= 1) lp += __shfl_xor(lp, off);
    __shared__ float wr[4];
    int lane = t & 63, w = t >> 6;
    if (!lane) wr[w] = lp;
    __syncthreads();
    if (t == 0) partials[b] = wr[0] + wr[1] + wr[2] + wr[3];
}

__global__ __launch_bounds__(256) void k_lossfin(const float* __restrict__ partials,
                                                 float* __restrict__ out0) {
    __shared__ double red[256];
    double s = 0.0;
    for (int i = threadIdx.x; i < 4096; i += 256) s += (double)partials[i];
    red[threadIdx.x] = s; __syncthreads();
    for (int st = 128; st; st >>= 1) {
        if (threadIdx.x < st) red[threadIdx.x] += red[threadIdx.x + st];
        __syncthreads();
    }
    if (!threadIdx.x) out0[0] = (float)(0.25 * red[0] / 16777216.0);
}

extern "C" void kernel_launch(void* const* d_in, const int* in_sizes, int n_in,
                              void* d_out, int out_size, void* d_ws, size_t ws_size,
                              hipStream_t stream) {
    const float* x   = (const float*)d_in[0];
    const float* E   = (const float*)d_in[1];
    const float* ecs = (const float*)d_in[2];
    const float* emw = (const float*)d_in[3];
    float* out = (float*)d_out;

    char* ws = (char*)d_ws;
    int*   idx      = (int*)(ws + 0);                  // 128 KB
    int*   bucket   = (int*)(ws + 131072);             // 128 KB
    float* en2      = (float*)(ws + 262144);           // 4 KB
    int*   counts   = (int*)(ws + 266240);             // 4 KB
    int*   offsets  = (int*)(ws + 270336);             // 4 KB
    int*   cursor   = (int*)(ws + 274432);             // 4 KB
    float* smoothed = (float*)(ws + 278528);           // 4 KB
    float* newE     = (float*)(ws + 282624);           // 2 MB
    float* partials = (float*)(ws + 282624 + 2097152); // 16 KB
    unsigned long long* packed = (unsigned long long*)newE;  // dead before k_fin

    float* out_loss = out;
    float* out_q    = out + 1;
    float* out_perp = out + 16777217;
    float* out_enc  = out + 16777218;

    // scratch in out_enc (128 MB, fully rewritten by k_qe afterwards):
    // efrag 2 MB + accb 2 MB
    short* efrag = (short*)out_enc;
    float* accb  = (float*)(out_enc + 524288);   // elements: 2 MB offset

    k_eprep  <<<KC / 32, 256, 0, stream>>>(E, efrag, en2, counts, packed, accb);
    k_argmin <<<(NROWS / 128) * 4, 256, 0, stream>>>(x, efrag, en2, packed);
    k_hist   <<<NROWS / 256, 256, 0, stream>>>(packed, idx, counts);
    k_meta   <<<1, 1024, 0, stream>>>(counts, ecs, smoothed, offsets, cursor, out_perp);
    k_scatter<<<NROWS / 256, 256, 0, stream>>>(idx, cursor, bucket);
    k_dwacc  <<<KC * 32, 256, 0, stream>>>(x, offsets, counts, bucket, accb);
    k_fin    <<<2048, 256, 0, stream>>>(accb, emw, smoothed, newE);
    k_qe     <<<NROWS / 8, 256, 0, stream>>>(x, idx, newE, out_q, out_enc, partials);
    k_lossfin<<<1, 256, 0, stream>>>(partials, out_loss);
}